// Round 6
// baseline (764.844 us; speedup 1.0000x reference)
//
#include <hip/hip_runtime.h>
#include <hip/hip_bf16.h>

#define NUM_USERS 100000
#define NUM_ITEMS 50000
#define EMBED     64
#define S_NNZ     (NUM_USERS * 32)
#define R_NNZ     (NUM_USERS * 50)
#define BATCH     8192

#define NPAD   100096            // scan width (multiple of 1024 > NUM_USERS)
#define SEGCAP 160               // per-slot R segment capacity (P(deg>160) ~ 1e-30)

// ---------------- direct CSR build: hist -> scan -> fetch-add scatter ----------------

// fused init: cntU=0, head=-1, bitmap=0, cntR=0
__global__ void k_zero(int* __restrict__ cntU, int* __restrict__ head,
                       unsigned* __restrict__ bitmap, int* __restrict__ cntR) {
    int i = blockIdx.x * blockDim.x + threadIdx.x;
    if (i < NPAD) cntU[i] = 0;
    if (i < NUM_USERS) head[i] = -1;
    if (i < (NUM_USERS + 31) / 32) bitmap[i] = 0;
    if (i < BATCH) cntR[i] = 0;
}

__global__ __launch_bounds__(256) void k_deghist(const int* __restrict__ rows,
                                                 int* __restrict__ cnt, int nnz) {
    int e = blockIdx.x * blockDim.x + threadIdx.x;
    if (e < nnz) atomicAdd(&cnt[rows[e]], 1);
}

// flat exclusive scan (in-place safe)
__global__ __launch_bounds__(1024) void k_scan1(const int* __restrict__ cnt, int* __restrict__ excl,
                                                int* __restrict__ bsums, int n) {
    __shared__ int buf[1024];
    int t = threadIdx.x;
    int i = blockIdx.x * 1024 + t;
    int x = (i < n) ? cnt[i] : 0;
    buf[t] = x;
    __syncthreads();
    for (int off = 1; off < 1024; off <<= 1) {
        int y = (t >= off) ? buf[t - off] : 0;
        __syncthreads();
        buf[t] += y;
        __syncthreads();
    }
    if (i < n) excl[i] = buf[t] - x;
    if (t == 1023) bsums[blockIdx.x] = buf[1023];
}

__global__ __launch_bounds__(1024) void k_scan2(int* __restrict__ bsums, int nb, int* __restrict__ total_slot) {
    __shared__ int buf[1024];
    int t = threadIdx.x;
    int x = (t < nb) ? bsums[t] : 0;
    buf[t] = x;
    __syncthreads();
    for (int off = 1; off < 1024; off <<= 1) {
        int y = (t >= off) ? buf[t - off] : 0;
        __syncthreads();
        buf[t] += y;
        __syncthreads();
    }
    if (t < nb) bsums[t] = buf[t] - x;
    if (t == 1023) total_slot[0] = buf[1023];
}

// finalize: rowptr[i] = cur[i] = excl[i] + block offset; rowptr[n] = S_NNZ
__global__ void k_scan3c(const int* __restrict__ excl, const int* __restrict__ bsums,
                         int* __restrict__ rowptr, int* __restrict__ cur, int n) {
    int i = blockIdx.x * blockDim.x + threadIdx.x;
    if (i < n) {
        int v = excl[i] + bsums[i >> 10];
        rowptr[i] = v;
        cur[i]    = v;
    }
    if (i == 0) rowptr[n] = S_NNZ;
}

// one-pass scatter: edges read once, fetch-add per-row cursor (100k addresses)
__global__ __launch_bounds__(256) void k_dscatter(const int* __restrict__ rows,
                                                  const int* __restrict__ cols,
                                                  const float* __restrict__ vals,
                                                  int* __restrict__ cur,
                                                  int2* __restrict__ colval, int nnz) {
    int e = blockIdx.x * blockDim.x + threadIdx.x;
    if (e >= nnz) return;
    int r   = rows[e];
    int pos = atomicAdd(&cur[r], 1);
    colval[pos] = make_int2(cols[e], __float_as_int(vals[e]));
}

// ---------------- converts ----------------
__global__ void k_cvt(const float* __restrict__ src, __hip_bfloat16* __restrict__ dst, int n) {
    int i = blockIdx.x * blockDim.x + threadIdx.x;
    if (i < n) dst[i] = __float2bfloat16(src[i]);
}

// ---------------- SpMM (CSR gather, bf16 table, unroll x8, nt edge stream) ----------------
__global__ __launch_bounds__(256) void k_spmm16(const int* __restrict__ rowptr,
                                                const int2* __restrict__ colval,
                                                const __hip_bfloat16* __restrict__ X,
                                                float* __restrict__ Y, int n_rows) {
    int w    = blockIdx.x * (blockDim.x >> 6) + (threadIdx.x >> 6);
    int lane = threadIdx.x & 63;
    if (w >= n_rows) return;
    int beg = rowptr[w], end = rowptr[w + 1];
    float acc = 0.0f;
    int j    = beg;
    int jend = beg + ((end - beg) & ~7);
    for (; j < jend; j += 8) {
        unsigned long long cv[8];
#pragma unroll
        for (int u = 0; u < 8; ++u)
            cv[u] = __builtin_nontemporal_load((const unsigned long long*)(colval + j + u));
        float x[8];
#pragma unroll
        for (int u = 0; u < 8; ++u)
            x[u] = __bfloat162float(X[(size_t)(unsigned)cv[u] * EMBED + lane]);
#pragma unroll
        for (int u = 0; u < 8; ++u)
            acc = fmaf(__int_as_float((int)(cv[u] >> 32)), x[u], acc);
    }
    for (; j < end; ++j) {
        int2 cv = colval[j];
        acc = fmaf(__int_as_float(cv.y), __bfloat162float(X[(size_t)cv.x * EMBED + lane]), acc);
    }
    Y[(size_t)w * EMBED + lane] = acc;
}

__global__ __launch_bounds__(256) void k_spmm_batch16(const int* __restrict__ rowptr,
                                                      const int2* __restrict__ colval,
                                                      const __hip_bfloat16* __restrict__ X,
                                                      const int* __restrict__ bu,
                                                      float* __restrict__ Agg2, int n) {
    int w    = blockIdx.x * (blockDim.x >> 6) + (threadIdx.x >> 6);
    int lane = threadIdx.x & 63;
    if (w >= n) return;
    int r   = bu[w];
    int beg = rowptr[r], end = rowptr[r + 1];
    float acc = 0.0f;
    int j    = beg;
    int jend = beg + ((end - beg) & ~7);
    for (; j < jend; j += 8) {
        int2 cv[8];
#pragma unroll
        for (int u = 0; u < 8; ++u) cv[u] = colval[j + u];
        float x[8];
#pragma unroll
        for (int u = 0; u < 8; ++u) x[u] = __bfloat162float(X[(size_t)cv[u].x * EMBED + lane]);
#pragma unroll
        for (int u = 0; u < 8; ++u) acc = fmaf(__int_as_float(cv[u].y), x[u], acc);
    }
    for (; j < end; ++j)
        acc = fmaf(__int_as_float(colval[j].y), __bfloat162float(X[(size_t)colval[j].x * EMBED + lane]), acc);
    Agg2[(size_t)w * EMBED + lane] = acc;
}

// ---------------- dense layers (v2) ----------------
// W transposed+XOR-swizzled in LDS; one conflict-free ds_read_b128 per 4 k-values,
// shared across 4 rows held in registers; X rows read as wave-uniform float4
// broadcasts from global (L1-resident).

__global__ __launch_bounds__(256) void k_layer(const float* __restrict__ Agg,
                                               const float* __restrict__ Uin,
                                               float* __restrict__ Uout,
                                               __hip_bfloat16* __restrict__ Uout16,
                                               const float* __restrict__ W,
                                               const float* __restrict__ b) {
    __shared__ __align__(16) float Wt[64 * 128];
    int t = threadIdx.x;
    for (int i = t; i < 128 * 64; i += 256) {
        int k = i >> 6, c = i & 63;
        Wt[c * 128 + ((((k >> 2) ^ (c & 7)) << 2) | (k & 3))] = W[i];
    }
    int rl = __builtin_amdgcn_readfirstlane(t >> 6);   // wave id 0..3 (wave-uniform)
    int c  = t & 63;
    int rbase = blockIdx.x * 16 + rl * 4;              // 6250*16 = 100000 exact, no guard
    __syncthreads();
    const float4* Wt4 = (const float4*)Wt;
    int  csw   = c & 7;
    int  cbase = c * 32;
    const float4* a0 = (const float4*)(Agg + (size_t)(rbase + 0) * EMBED);
    const float4* a1 = (const float4*)(Agg + (size_t)(rbase + 1) * EMBED);
    const float4* a2 = (const float4*)(Agg + (size_t)(rbase + 2) * EMBED);
    const float4* a3 = (const float4*)(Agg + (size_t)(rbase + 3) * EMBED);
    const float4* u0 = (const float4*)(Uin + (size_t)(rbase + 0) * EMBED);
    const float4* u1 = (const float4*)(Uin + (size_t)(rbase + 1) * EMBED);
    const float4* u2 = (const float4*)(Uin + (size_t)(rbase + 2) * EMBED);
    const float4* u3 = (const float4*)(Uin + (size_t)(rbase + 3) * EMBED);
    float bias = b[c];
    float acc0 = bias, acc1 = bias, acc2 = bias, acc3 = bias;
#pragma unroll 4
    for (int k4 = 0; k4 < 16; ++k4) {
        float4 w4 = Wt4[cbase + (k4 ^ csw)];
        float4 x0 = a0[k4], x1 = a1[k4], x2 = a2[k4], x3 = a3[k4];
        acc0 = fmaf(x0.x, w4.x, acc0); acc0 = fmaf(x0.y, w4.y, acc0); acc0 = fmaf(x0.z, w4.z, acc0); acc0 = fmaf(x0.w, w4.w, acc0);
        acc1 = fmaf(x1.x, w4.x, acc1); acc1 = fmaf(x1.y, w4.y, acc1); acc1 = fmaf(x1.z, w4.z, acc1); acc1 = fmaf(x1.w, w4.w, acc1);
        acc2 = fmaf(x2.x, w4.x, acc2); acc2 = fmaf(x2.y, w4.y, acc2); acc2 = fmaf(x2.z, w4.z, acc2); acc2 = fmaf(x2.w, w4.w, acc2);
        acc3 = fmaf(x3.x, w4.x, acc3); acc3 = fmaf(x3.y, w4.y, acc3); acc3 = fmaf(x3.z, w4.z, acc3); acc3 = fmaf(x3.w, w4.w, acc3);
    }
#pragma unroll 4
    for (int k4 = 16; k4 < 32; ++k4) {
        float4 w4 = Wt4[cbase + (k4 ^ csw)];
        float4 x0 = u0[k4 - 16], x1 = u1[k4 - 16], x2 = u2[k4 - 16], x3 = u3[k4 - 16];
        acc0 = fmaf(x0.x, w4.x, acc0); acc0 = fmaf(x0.y, w4.y, acc0); acc0 = fmaf(x0.z, w4.z, acc0); acc0 = fmaf(x0.w, w4.w, acc0);
        acc1 = fmaf(x1.x, w4.x, acc1); acc1 = fmaf(x1.y, w4.y, acc1); acc1 = fmaf(x1.z, w4.z, acc1); acc1 = fmaf(x1.w, w4.w, acc1);
        acc2 = fmaf(x2.x, w4.x, acc2); acc2 = fmaf(x2.y, w4.y, acc2); acc2 = fmaf(x2.z, w4.z, acc2); acc2 = fmaf(x2.w, w4.w, acc2);
        acc3 = fmaf(x3.x, w4.x, acc3); acc3 = fmaf(x3.y, w4.y, acc3); acc3 = fmaf(x3.z, w4.z, acc3); acc3 = fmaf(x3.w, w4.w, acc3);
    }
    float v0 = fmaxf(acc0, 0.0f), v1 = fmaxf(acc1, 0.0f), v2 = fmaxf(acc2, 0.0f), v3 = fmaxf(acc3, 0.0f);
    Uout[(size_t)(rbase + 0) * EMBED + c] = v0;
    Uout[(size_t)(rbase + 1) * EMBED + c] = v1;
    Uout[(size_t)(rbase + 2) * EMBED + c] = v2;
    Uout[(size_t)(rbase + 3) * EMBED + c] = v3;
    Uout16[(size_t)(rbase + 0) * EMBED + c] = __float2bfloat16(v0);
    Uout16[(size_t)(rbase + 1) * EMBED + c] = __float2bfloat16(v1);
    Uout16[(size_t)(rbase + 2) * EMBED + c] = __float2bfloat16(v2);
    Uout16[(size_t)(rbase + 3) * EMBED + c] = __float2bfloat16(v3);
}

__global__ __launch_bounds__(256) void k_layer_batch(const float* __restrict__ Agg2,
                                                     const float* __restrict__ Uin,
                                                     const int* __restrict__ bu,
                                                     float* __restrict__ out0,
                                                     const float* __restrict__ W,
                                                     const float* __restrict__ b) {
    __shared__ __align__(16) float Wt[64 * 128];
    int t = threadIdx.x;
    for (int i = t; i < 128 * 64; i += 256) {
        int k = i >> 6, c = i & 63;
        Wt[c * 128 + ((((k >> 2) ^ (c & 7)) << 2) | (k & 3))] = W[i];
    }
    int rl = __builtin_amdgcn_readfirstlane(t >> 6);
    int c  = t & 63;
    int sbase = blockIdx.x * 16 + rl * 4;              // 512*16 = 8192 exact
    int r0 = bu[sbase + 0], r1 = bu[sbase + 1], r2 = bu[sbase + 2], r3 = bu[sbase + 3];
    __syncthreads();
    const float4* Wt4 = (const float4*)Wt;
    int  csw   = c & 7;
    int  cbase = c * 32;
    const float4* a0 = (const float4*)(Agg2 + (size_t)(sbase + 0) * EMBED);
    const float4* a1 = (const float4*)(Agg2 + (size_t)(sbase + 1) * EMBED);
    const float4* a2 = (const float4*)(Agg2 + (size_t)(sbase + 2) * EMBED);
    const float4* a3 = (const float4*)(Agg2 + (size_t)(sbase + 3) * EMBED);
    const float4* u0 = (const float4*)(Uin + (size_t)r0 * EMBED);
    const float4* u1 = (const float4*)(Uin + (size_t)r1 * EMBED);
    const float4* u2 = (const float4*)(Uin + (size_t)r2 * EMBED);
    const float4* u3 = (const float4*)(Uin + (size_t)r3 * EMBED);
    float bias = b[c];
    float acc0 = bias, acc1 = bias, acc2 = bias, acc3 = bias;
#pragma unroll 4
    for (int k4 = 0; k4 < 16; ++k4) {
        float4 w4 = Wt4[cbase + (k4 ^ csw)];
        float4 x0 = a0[k4], x1 = a1[k4], x2 = a2[k4], x3 = a3[k4];
        acc0 = fmaf(x0.x, w4.x, acc0); acc0 = fmaf(x0.y, w4.y, acc0); acc0 = fmaf(x0.z, w4.z, acc0); acc0 = fmaf(x0.w, w4.w, acc0);
        acc1 = fmaf(x1.x, w4.x, acc1); acc1 = fmaf(x1.y, w4.y, acc1); acc1 = fmaf(x1.z, w4.z, acc1); acc1 = fmaf(x1.w, w4.w, acc1);
        acc2 = fmaf(x2.x, w4.x, acc2); acc2 = fmaf(x2.y, w4.y, acc2); acc2 = fmaf(x2.z, w4.z, acc2); acc2 = fmaf(x2.w, w4.w, acc2);
        acc3 = fmaf(x3.x, w4.x, acc3); acc3 = fmaf(x3.y, w4.y, acc3); acc3 = fmaf(x3.z, w4.z, acc3); acc3 = fmaf(x3.w, w4.w, acc3);
    }
#pragma unroll 4
    for (int k4 = 16; k4 < 32; ++k4) {
        float4 w4 = Wt4[cbase + (k4 ^ csw)];
        float4 x0 = u0[k4 - 16], x1 = u1[k4 - 16], x2 = u2[k4 - 16], x3 = u3[k4 - 16];
        acc0 = fmaf(x0.x, w4.x, acc0); acc0 = fmaf(x0.y, w4.y, acc0); acc0 = fmaf(x0.z, w4.z, acc0); acc0 = fmaf(x0.w, w4.w, acc0);
        acc1 = fmaf(x1.x, w4.x, acc1); acc1 = fmaf(x1.y, w4.y, acc1); acc1 = fmaf(x1.z, w4.z, acc1); acc1 = fmaf(x1.w, w4.w, acc1);
        acc2 = fmaf(x2.x, w4.x, acc2); acc2 = fmaf(x2.y, w4.y, acc2); acc2 = fmaf(x2.z, w4.z, acc2); acc2 = fmaf(x2.w, w4.w, acc2);
        acc3 = fmaf(x3.x, w4.x, acc3); acc3 = fmaf(x3.y, w4.y, acc3); acc3 = fmaf(x3.z, w4.z, acc3); acc3 = fmaf(x3.w, w4.w, acc3);
    }
    out0[(size_t)(sbase + 0) * EMBED + c] = fmaxf(acc0, 0.0f);
    out0[(size_t)(sbase + 1) * EMBED + c] = fmaxf(acc1, 0.0f);
    out0[(size_t)(sbase + 2) * EMBED + c] = fmaxf(acc2, 0.0f);
    out0[(size_t)(sbase + 3) * EMBED + c] = fmaxf(acc3, 0.0f);
}

// ---------------- R handling: bitmap filter -> fixed segments -> register SpMM ----------------

__global__ void k_chain(const int* __restrict__ bu, int* __restrict__ head,
                        int* __restrict__ nxt, unsigned* __restrict__ bitmap, int n) {
    int i = blockIdx.x * blockDim.x + threadIdx.x;
    if (i < n) {
        int u = bu[i];
        nxt[i] = atomicExch(&head[u], i);
        atomicOr(&bitmap[u >> 5], 1u << (u & 31));
    }
}

// single pass: matched edges -> seg[slot*SEGCAP + cnt++]
__global__ __launch_bounds__(256) void k_rseg(const int* __restrict__ rows,
                                              const int* __restrict__ cols,
                                              const float* __restrict__ vals,
                                              const unsigned* __restrict__ bitmap,
                                              const int* __restrict__ head,
                                              int* __restrict__ cntR,
                                              int2* __restrict__ seg, int nnz) {
    int e = blockIdx.x * blockDim.x + threadIdx.x;
    if (e >= nnz) return;
    int r = rows[e];
    if (!((bitmap[(unsigned)r >> 5] >> (r & 31)) & 1u)) return;
    int s   = head[r];
    int pos = atomicAdd(&cntR[s], 1);
    if (pos < SEGCAP) seg[s * SEGCAP + pos] = make_int2(cols[e], __float_as_int(vals[e]));
}

// per-chain-head gather SpMM over its segment; write once per slot along chain
__global__ __launch_bounds__(256) void k_rspmm(const int* __restrict__ cntR,
                                               const int2* __restrict__ seg,
                                               const __hip_bfloat16* __restrict__ V16,
                                               const int* __restrict__ bu,
                                               const int* __restrict__ head,
                                               const int* __restrict__ nxt,
                                               float* __restrict__ out0) {
    int s    = blockIdx.x * (blockDim.x >> 6) + (threadIdx.x >> 6);
    int lane = threadIdx.x & 63;
    if (s >= BATCH) return;
    if (head[bu[s]] != s) return;       // only chain heads own edges
    int n = cntR[s];
    if (n > SEGCAP) n = SEGCAP;
    const int2* cv2 = seg + (size_t)s * SEGCAP;
    float acc = 0.0f;
    int j    = 0;
    int jend = n & ~7;
    for (; j < jend; j += 8) {
        int2 cv[8];
#pragma unroll
        for (int u = 0; u < 8; ++u) cv[u] = cv2[j + u];
        float x[8];
#pragma unroll
        for (int u = 0; u < 8; ++u) x[u] = __bfloat162float(V16[(size_t)cv[u].x * EMBED + lane]);
#pragma unroll
        for (int u = 0; u < 8; ++u) acc = fmaf(__int_as_float(cv[u].y), x[u], acc);
    }
    for (; j < n; ++j)
        acc = fmaf(__int_as_float(cv2[j].y), __bfloat162float(V16[(size_t)cv2[j].x * EMBED + lane]), acc);
    int slot = s;
    while (slot >= 0) {
        out0[(size_t)slot * EMBED + lane] += acc;
        slot = nxt[slot];
    }
}

// ---------------- final gathers (bp/bn only, exact fp32 V) ----------------
__global__ void k_gather2(const float* __restrict__ V,
                          const int* __restrict__ bp, const int* __restrict__ bn,
                          float* __restrict__ out) {
    int i = blockIdx.x * blockDim.x + threadIdx.x;
    if (i >= BATCH * EMBED) return;
    int row = i >> 6, l = i & 63;
    out[BATCH * EMBED + i]     = V[(size_t)bp[row] * EMBED + l];
    out[2 * BATCH * EMBED + i] = V[(size_t)bn[row] * EMBED + l];
}

// ---------------- launch ----------------

extern "C" void kernel_launch(void* const* d_in, const int* in_sizes, int n_in,
                              void* d_out, int out_size, void* d_ws, size_t ws_size,
                              hipStream_t stream) {
    const int*   batch_user = (const int*)d_in[0];
    const int*   batch_pos  = (const int*)d_in[1];
    const int*   batch_neg  = (const int*)d_in[2];
    const float* U     = (const float*)d_in[3];
    const float* V     = (const float*)d_in[4];
    const float* W0    = (const float*)d_in[5];
    const float* b0    = (const float*)d_in[6];
    const float* W1    = (const float*)d_in[7];
    const float* b1    = (const float*)d_in[8];
    const int*   S_row = (const int*)d_in[9];
    const int*   S_col = (const int*)d_in[10];
    const float* S_val = (const float*)d_in[11];
    const int*   R_row = (const int*)d_in[12];
    const int*   R_col = (const int*)d_in[13];
    const float* R_val = (const float*)d_in[14];
    float* out = (float*)d_out;

    const size_t tabElems = (size_t)NUM_USERS * EMBED;   // 6.4M

    // workspace layout. Aliases: seg <- B (B dead after k_layer).
    // X16 region (12.8 MB) sequentially holds U16 -> A16 -> V16.
    char* wsb = (char*)d_ws;
    size_t o = 0;
    float* A       = (float*)(wsb + o); o += tabElems * 4;            // U1 fp32
    float* B       = (float*)(wsb + o); o += tabElems * 4;            // agg fp32 (alias: seg)
    float* Agg2    = (float*)(wsb + o); o += (size_t)BATCH * EMBED * 4;
    int*   rowptrS = (int*)(wsb + o);   o += (NUM_USERS + 1) * 4;
    int*   cntU    = (int*)(wsb + o);   o += NPAD * 4;
    int*   curU    = (int*)(wsb + o);   o += NUM_USERS * 4;
    int*   bsums   = (int*)(wsb + o);   o += 1024 * 4;
    int*   head    = (int*)(wsb + o);   o += NUM_USERS * 4;
    int*   nxt     = (int*)(wsb + o);   o += BATCH * 4;
    int*   cntR    = (int*)(wsb + o);   o += BATCH * 4;
    unsigned* bitmap = (unsigned*)(wsb + o); o += ((NUM_USERS + 31) / 32) * 4;
    o = (o + 7) & ~(size_t)7;
    int2*  colvalS = (int2*)(wsb + o);  o += (size_t)S_NNZ * 8;
    __hip_bfloat16* X16 = (__hip_bfloat16*)(wsb + o); o += tabElems * 2;

    int2* seg = (int2*)B;   // alias: B dead after k_layer; 8192*160*8B = 10.5MB < 25.6MB

    const int spmm_blocks  = (NUM_USERS * 64 + 255) / 256;
    const int layer_blocks = (NUM_USERS + 15) / 16;
    const int scan_blocks  = (NUM_USERS + 1023) / 1024;   // 98

    // ---- init (cntU/head/bitmap/cntR) ----
    k_zero<<<(NPAD + 255) / 256, 256, 0, stream>>>(cntU, head, bitmap, cntR);

    // ---- CSR of S: direct hist -> scan -> fetch-add scatter ----
    k_deghist<<<(S_NNZ + 255) / 256, 256, 0, stream>>>(S_row, cntU, S_NNZ);
    k_scan1<<<scan_blocks, 1024, 0, stream>>>(cntU, cntU, bsums, NUM_USERS);
    k_scan2<<<1, 1024, 0, stream>>>(bsums, scan_blocks, &bsums[512]);
    k_scan3c<<<(NUM_USERS + 255) / 256, 256, 0, stream>>>(cntU, bsums, rowptrS, curU, NUM_USERS);
    k_dscatter<<<(S_NNZ + 255) / 256, 256, 0, stream>>>(S_row, S_col, S_val, curU, colvalS, S_NNZ);

    // ---- layer 0 (full): U16 table, SpMM1, layer v2 (emits A + A16) ----
    k_cvt<<<(int)((tabElems + 255) / 256), 256, 0, stream>>>(U, X16, (int)tabElems);
    k_spmm16<<<spmm_blocks, 256, 0, stream>>>(rowptrS, colvalS, X16, B, NUM_USERS);
    k_layer<<<layer_blocks, 256, 0, stream>>>(B, U, A, X16, W0, b0);   // X16 now = A16; B dead

    // ---- chain map + batch bitmap for R (user -> batch slots) ----
    k_chain<<<(BATCH + 255) / 256, 256, 0, stream>>>(batch_user, head, nxt, bitmap, BATCH);

    // ---- layer 1 (batch-restricted), writes u2 into out0 ----
    k_spmm_batch16<<<(BATCH * 64 + 255) / 256, 256, 0, stream>>>(rowptrS, colvalS, X16, batch_user, Agg2, BATCH);
    k_layer_batch<<<(BATCH + 15) / 16, 256, 0, stream>>>(Agg2, A, batch_user, out, W1, b1);  // A dead

    // ---- out0 += (R @ V)[batch rows]: bitmap filter -> segments -> SpMM ----
    k_rseg<<<(R_NNZ + 255) / 256, 256, 0, stream>>>(R_row, R_col, R_val, bitmap, head, cntR, seg, R_NNZ);
    k_cvt<<<(int)(((size_t)NUM_ITEMS * EMBED + 255) / 256), 256, 0, stream>>>(V, X16, NUM_ITEMS * EMBED); // X16 now = V16
    k_rspmm<<<(BATCH * 64 + 255) / 256, 256, 0, stream>>>(cntR, seg, X16, batch_user, head, nxt, out);

    // ---- bp/bn gathers (exact fp32 V) ----
    k_gather2<<<(BATCH * EMBED + 255) / 256, 256, 0, stream>>>(V, batch_pos, batch_neg, out);
}

// Round 7
// 577.370 us; speedup vs baseline: 1.3247x; 1.3247x over previous
//
#include <hip/hip_runtime.h>
#include <hip/hip_bf16.h>

#define NUM_USERS 100000
#define NUM_ITEMS 50000
#define EMBED     64
#define S_NNZ     (NUM_USERS * 32)
#define R_NNZ     (NUM_USERS * 50)
#define BATCH     8192

// bucket sort parameters: 256 buckets x 391 rows, 256 chunks x 12500 edges
#define NB    256
#define NCH   256
#define CHUNK (S_NNZ / NCH)      // 12500
#define BROWS 391                // 391*256 = 100096 >= NUM_USERS

// ---------------- two-pass bucket CSR build ----------------

__global__ __launch_bounds__(256) void k_p1hist(const int* __restrict__ rows, int* __restrict__ cnt_t) {
    __shared__ int h[NB];
    int t = threadIdx.x, b = blockIdx.x;
    h[t] = 0;
    __syncthreads();
    int base = b * CHUNK;
    for (int i = t; i < CHUNK; i += 256) atomicAdd(&h[rows[base + i] / BROWS], 1);
    __syncthreads();
    cnt_t[t * NCH + b] = h[t];
}

__global__ __launch_bounds__(1024) void k_scan1(const int* __restrict__ cnt, int* __restrict__ excl,
                                                int* __restrict__ bsums, int n) {
    __shared__ int buf[1024];
    int t = threadIdx.x;
    int i = blockIdx.x * 1024 + t;
    int x = (i < n) ? cnt[i] : 0;
    buf[t] = x;
    __syncthreads();
    for (int off = 1; off < 1024; off <<= 1) {
        int y = (t >= off) ? buf[t - off] : 0;
        __syncthreads();
        buf[t] += y;
        __syncthreads();
    }
    if (i < n) excl[i] = buf[t] - x;
    if (t == 1023) bsums[blockIdx.x] = buf[1023];
}

__global__ __launch_bounds__(1024) void k_scan2(int* __restrict__ bsums, int nb, int* __restrict__ total_slot) {
    __shared__ int buf[1024];
    int t = threadIdx.x;
    int x = (t < nb) ? bsums[t] : 0;
    buf[t] = x;
    __syncthreads();
    for (int off = 1; off < 1024; off <<= 1) {
        int y = (t >= off) ? buf[t - off] : 0;
        __syncthreads();
        buf[t] += y;
        __syncthreads();
    }
    if (t < nb) bsums[t] = buf[t] - x;
    if (t == 1023) total_slot[0] = buf[1023];
}

__global__ void k_scan3b(int* __restrict__ a, const int* __restrict__ bsums, int n) {
    int i = blockIdx.x * blockDim.x + threadIdx.x;
    if (i < n) a[i] += bsums[i >> 10];
}

__global__ __launch_bounds__(256) void k_p1scatter(const int* __restrict__ rows, const int* __restrict__ cols,
                                                   const float* __restrict__ vals, const int* __restrict__ cnt_t,
                                                   int2* __restrict__ tmpE) {
    __shared__ int cur[NB];
    int t = threadIdx.x, b = blockIdx.x;
    cur[t] = cnt_t[t * NCH + b];
    __syncthreads();
    int base = b * CHUNK;
    for (int i = t; i < CHUNK; i += 256) {
        int e  = base + i;
        int r  = rows[e];
        int bk = r / BROWS;
        int pos = atomicAdd(&cur[bk], 1);
        tmpE[pos] = make_int2(((r - bk * BROWS) << 17) | cols[e], __float_as_int(vals[e]));
    }
}

__global__ __launch_bounds__(512) void k_p2(const int2* __restrict__ tmpE, const int* __restrict__ cnt_t,
                                            int* __restrict__ rowptr, int2* __restrict__ colval) {
    __shared__ int h[512];
    __shared__ int s[512];
    __shared__ int cur[512];
    int t = threadIdx.x, k = blockIdx.x;
    int beg = cnt_t[k * NCH];
    int end = (k < NB - 1) ? cnt_t[(k + 1) * NCH] : S_NNZ;
    h[t] = 0;
    __syncthreads();
    for (int j = beg + t; j < end; j += 512) atomicAdd(&h[((unsigned)tmpE[j].x) >> 17], 1);
    __syncthreads();
    s[t] = h[t];
    __syncthreads();
    for (int off = 1; off < 512; off <<= 1) {
        int y = (t >= off) ? s[t - off] : 0;
        __syncthreads();
        s[t] += y;
        __syncthreads();
    }
    int excl = s[t] - h[t];
    int gr   = k * BROWS + t;
    if (t <= BROWS && gr <= NUM_USERS) rowptr[gr] = beg + excl;
    cur[t] = beg + excl;
    __syncthreads();
    for (int j = beg + t; j < end; j += 512) {
        int2 e  = tmpE[j];
        int pos = atomicAdd(&cur[((unsigned)e.x) >> 17], 1);
        colval[pos] = make_int2(e.x & 0x1FFFF, e.y);
    }
}

// ---------------- converts ----------------
__global__ void k_cvt(const float* __restrict__ src, __hip_bfloat16* __restrict__ dst, int n) {
    int i = blockIdx.x * blockDim.x + threadIdx.x;
    if (i < n) dst[i] = __float2bfloat16(src[i]);
}

// ---------------- SpMM (CSR gather, bf16 table, unroll x8, nt edge stream) ----------------
__global__ __launch_bounds__(256) void k_spmm16(const int* __restrict__ rowptr,
                                                const int2* __restrict__ colval,
                                                const __hip_bfloat16* __restrict__ X,
                                                float* __restrict__ Y, int n_rows) {
    int w    = blockIdx.x * (blockDim.x >> 6) + (threadIdx.x >> 6);
    int lane = threadIdx.x & 63;
    if (w >= n_rows) return;
    int beg = rowptr[w], end = rowptr[w + 1];
    float acc = 0.0f;
    int j    = beg;
    int jend = beg + ((end - beg) & ~7);
    for (; j < jend; j += 8) {
        unsigned long long cv[8];
#pragma unroll
        for (int u = 0; u < 8; ++u)
            cv[u] = __builtin_nontemporal_load((const unsigned long long*)(colval + j + u));
        float x[8];
#pragma unroll
        for (int u = 0; u < 8; ++u)
            x[u] = __bfloat162float(X[(size_t)(unsigned)cv[u] * EMBED + lane]);
#pragma unroll
        for (int u = 0; u < 8; ++u)
            acc = fmaf(__int_as_float((int)(cv[u] >> 32)), x[u], acc);
    }
    for (; j < end; ++j) {
        int2 cv = colval[j];
        acc = fmaf(__int_as_float(cv.y), __bfloat162float(X[(size_t)cv.x * EMBED + lane]), acc);
    }
    Y[(size_t)w * EMBED + lane] = acc;
}

__global__ __launch_bounds__(256) void k_spmm_batch16(const int* __restrict__ rowptr,
                                                      const int2* __restrict__ colval,
                                                      const __hip_bfloat16* __restrict__ X,
                                                      const int* __restrict__ bu,
                                                      float* __restrict__ Agg2, int n) {
    int w    = blockIdx.x * (blockDim.x >> 6) + (threadIdx.x >> 6);
    int lane = threadIdx.x & 63;
    if (w >= n) return;
    int r   = bu[w];
    int beg = rowptr[r], end = rowptr[r + 1];
    float acc = 0.0f;
    int j    = beg;
    int jend = beg + ((end - beg) & ~7);
    for (; j < jend; j += 8) {
        int2 cv[8];
#pragma unroll
        for (int u = 0; u < 8; ++u) cv[u] = colval[j + u];
        float x[8];
#pragma unroll
        for (int u = 0; u < 8; ++u) x[u] = __bfloat162float(X[(size_t)cv[u].x * EMBED + lane]);
#pragma unroll
        for (int u = 0; u < 8; ++u) acc = fmaf(__int_as_float(cv[u].y), x[u], acc);
    }
    for (; j < end; ++j)
        acc = fmaf(__int_as_float(colval[j].y), __bfloat162float(X[(size_t)colval[j].x * EMBED + lane]), acc);
    Agg2[(size_t)w * EMBED + lane] = acc;
}

// ---------------- dense layers (v2) ----------------
// W transposed+XOR-swizzled in LDS; one conflict-free ds_read_b128 per 4 k-values,
// shared across 4 rows held in registers; X rows read as wave-uniform float4
// broadcasts from global (L1-resident).

__global__ __launch_bounds__(256) void k_layer(const float* __restrict__ Agg,
                                               const float* __restrict__ Uin,
                                               float* __restrict__ Uout,
                                               __hip_bfloat16* __restrict__ Uout16,
                                               const float* __restrict__ W,
                                               const float* __restrict__ b) {
    __shared__ __align__(16) float Wt[64 * 128];
    int t = threadIdx.x;
    for (int i = t; i < 128 * 64; i += 256) {
        int k = i >> 6, c = i & 63;
        Wt[c * 128 + ((((k >> 2) ^ (c & 7)) << 2) | (k & 3))] = W[i];
    }
    int rl = __builtin_amdgcn_readfirstlane(t >> 6);   // wave id 0..3 (wave-uniform)
    int c  = t & 63;
    int rbase = blockIdx.x * 16 + rl * 4;              // 6250*16 = 100000 exact, no guard
    __syncthreads();
    const float4* Wt4 = (const float4*)Wt;
    int  csw   = c & 7;
    int  cbase = c * 32;
    const float4* a0 = (const float4*)(Agg + (size_t)(rbase + 0) * EMBED);
    const float4* a1 = (const float4*)(Agg + (size_t)(rbase + 1) * EMBED);
    const float4* a2 = (const float4*)(Agg + (size_t)(rbase + 2) * EMBED);
    const float4* a3 = (const float4*)(Agg + (size_t)(rbase + 3) * EMBED);
    const float4* u0 = (const float4*)(Uin + (size_t)(rbase + 0) * EMBED);
    const float4* u1 = (const float4*)(Uin + (size_t)(rbase + 1) * EMBED);
    const float4* u2 = (const float4*)(Uin + (size_t)(rbase + 2) * EMBED);
    const float4* u3 = (const float4*)(Uin + (size_t)(rbase + 3) * EMBED);
    float bias = b[c];
    float acc0 = bias, acc1 = bias, acc2 = bias, acc3 = bias;
#pragma unroll 4
    for (int k4 = 0; k4 < 16; ++k4) {
        float4 w4 = Wt4[cbase + (k4 ^ csw)];
        float4 x0 = a0[k4], x1 = a1[k4], x2 = a2[k4], x3 = a3[k4];
        acc0 = fmaf(x0.x, w4.x, acc0); acc0 = fmaf(x0.y, w4.y, acc0); acc0 = fmaf(x0.z, w4.z, acc0); acc0 = fmaf(x0.w, w4.w, acc0);
        acc1 = fmaf(x1.x, w4.x, acc1); acc1 = fmaf(x1.y, w4.y, acc1); acc1 = fmaf(x1.z, w4.z, acc1); acc1 = fmaf(x1.w, w4.w, acc1);
        acc2 = fmaf(x2.x, w4.x, acc2); acc2 = fmaf(x2.y, w4.y, acc2); acc2 = fmaf(x2.z, w4.z, acc2); acc2 = fmaf(x2.w, w4.w, acc2);
        acc3 = fmaf(x3.x, w4.x, acc3); acc3 = fmaf(x3.y, w4.y, acc3); acc3 = fmaf(x3.z, w4.z, acc3); acc3 = fmaf(x3.w, w4.w, acc3);
    }
#pragma unroll 4
    for (int k4 = 16; k4 < 32; ++k4) {
        float4 w4 = Wt4[cbase + (k4 ^ csw)];
        float4 x0 = u0[k4 - 16], x1 = u1[k4 - 16], x2 = u2[k4 - 16], x3 = u3[k4 - 16];
        acc0 = fmaf(x0.x, w4.x, acc0); acc0 = fmaf(x0.y, w4.y, acc0); acc0 = fmaf(x0.z, w4.z, acc0); acc0 = fmaf(x0.w, w4.w, acc0);
        acc1 = fmaf(x1.x, w4.x, acc1); acc1 = fmaf(x1.y, w4.y, acc1); acc1 = fmaf(x1.z, w4.z, acc1); acc1 = fmaf(x1.w, w4.w, acc1);
        acc2 = fmaf(x2.x, w4.x, acc2); acc2 = fmaf(x2.y, w4.y, acc2); acc2 = fmaf(x2.z, w4.z, acc2); acc2 = fmaf(x2.w, w4.w, acc2);
        acc3 = fmaf(x3.x, w4.x, acc3); acc3 = fmaf(x3.y, w4.y, acc3); acc3 = fmaf(x3.z, w4.z, acc3); acc3 = fmaf(x3.w, w4.w, acc3);
    }
    float v0 = fmaxf(acc0, 0.0f), v1 = fmaxf(acc1, 0.0f), v2 = fmaxf(acc2, 0.0f), v3 = fmaxf(acc3, 0.0f);
    Uout[(size_t)(rbase + 0) * EMBED + c] = v0;
    Uout[(size_t)(rbase + 1) * EMBED + c] = v1;
    Uout[(size_t)(rbase + 2) * EMBED + c] = v2;
    Uout[(size_t)(rbase + 3) * EMBED + c] = v3;
    Uout16[(size_t)(rbase + 0) * EMBED + c] = __float2bfloat16(v0);
    Uout16[(size_t)(rbase + 1) * EMBED + c] = __float2bfloat16(v1);
    Uout16[(size_t)(rbase + 2) * EMBED + c] = __float2bfloat16(v2);
    Uout16[(size_t)(rbase + 3) * EMBED + c] = __float2bfloat16(v3);
}

__global__ __launch_bounds__(256) void k_layer_batch(const float* __restrict__ Agg2,
                                                     const float* __restrict__ Uin,
                                                     const int* __restrict__ bu,
                                                     float* __restrict__ out0,
                                                     const float* __restrict__ W,
                                                     const float* __restrict__ b) {
    __shared__ __align__(16) float Wt[64 * 128];
    int t = threadIdx.x;
    for (int i = t; i < 128 * 64; i += 256) {
        int k = i >> 6, c = i & 63;
        Wt[c * 128 + ((((k >> 2) ^ (c & 7)) << 2) | (k & 3))] = W[i];
    }
    int rl = __builtin_amdgcn_readfirstlane(t >> 6);
    int c  = t & 63;
    int sbase = blockIdx.x * 16 + rl * 4;              // 512*16 = 8192 exact
    int r0 = bu[sbase + 0], r1 = bu[sbase + 1], r2 = bu[sbase + 2], r3 = bu[sbase + 3];
    __syncthreads();
    const float4* Wt4 = (const float4*)Wt;
    int  csw   = c & 7;
    int  cbase = c * 32;
    const float4* a0 = (const float4*)(Agg2 + (size_t)(sbase + 0) * EMBED);
    const float4* a1 = (const float4*)(Agg2 + (size_t)(sbase + 1) * EMBED);
    const float4* a2 = (const float4*)(Agg2 + (size_t)(sbase + 2) * EMBED);
    const float4* a3 = (const float4*)(Agg2 + (size_t)(sbase + 3) * EMBED);
    const float4* u0 = (const float4*)(Uin + (size_t)r0 * EMBED);
    const float4* u1 = (const float4*)(Uin + (size_t)r1 * EMBED);
    const float4* u2 = (const float4*)(Uin + (size_t)r2 * EMBED);
    const float4* u3 = (const float4*)(Uin + (size_t)r3 * EMBED);
    float bias = b[c];
    float acc0 = bias, acc1 = bias, acc2 = bias, acc3 = bias;
#pragma unroll 4
    for (int k4 = 0; k4 < 16; ++k4) {
        float4 w4 = Wt4[cbase + (k4 ^ csw)];
        float4 x0 = a0[k4], x1 = a1[k4], x2 = a2[k4], x3 = a3[k4];
        acc0 = fmaf(x0.x, w4.x, acc0); acc0 = fmaf(x0.y, w4.y, acc0); acc0 = fmaf(x0.z, w4.z, acc0); acc0 = fmaf(x0.w, w4.w, acc0);
        acc1 = fmaf(x1.x, w4.x, acc1); acc1 = fmaf(x1.y, w4.y, acc1); acc1 = fmaf(x1.z, w4.z, acc1); acc1 = fmaf(x1.w, w4.w, acc1);
        acc2 = fmaf(x2.x, w4.x, acc2); acc2 = fmaf(x2.y, w4.y, acc2); acc2 = fmaf(x2.z, w4.z, acc2); acc2 = fmaf(x2.w, w4.w, acc2);
        acc3 = fmaf(x3.x, w4.x, acc3); acc3 = fmaf(x3.y, w4.y, acc3); acc3 = fmaf(x3.z, w4.z, acc3); acc3 = fmaf(x3.w, w4.w, acc3);
    }
#pragma unroll 4
    for (int k4 = 16; k4 < 32; ++k4) {
        float4 w4 = Wt4[cbase + (k4 ^ csw)];
        float4 x0 = u0[k4 - 16], x1 = u1[k4 - 16], x2 = u2[k4 - 16], x3 = u3[k4 - 16];
        acc0 = fmaf(x0.x, w4.x, acc0); acc0 = fmaf(x0.y, w4.y, acc0); acc0 = fmaf(x0.z, w4.z, acc0); acc0 = fmaf(x0.w, w4.w, acc0);
        acc1 = fmaf(x1.x, w4.x, acc1); acc1 = fmaf(x1.y, w4.y, acc1); acc1 = fmaf(x1.z, w4.z, acc1); acc1 = fmaf(x1.w, w4.w, acc1);
        acc2 = fmaf(x2.x, w4.x, acc2); acc2 = fmaf(x2.y, w4.y, acc2); acc2 = fmaf(x2.z, w4.z, acc2); acc2 = fmaf(x2.w, w4.w, acc2);
        acc3 = fmaf(x3.x, w4.x, acc3); acc3 = fmaf(x3.y, w4.y, acc3); acc3 = fmaf(x3.z, w4.z, acc3); acc3 = fmaf(x3.w, w4.w, acc3);
    }
    out0[(size_t)(sbase + 0) * EMBED + c] = fmaxf(acc0, 0.0f);
    out0[(size_t)(sbase + 1) * EMBED + c] = fmaxf(acc1, 0.0f);
    out0[(size_t)(sbase + 2) * EMBED + c] = fmaxf(acc2, 0.0f);
    out0[(size_t)(sbase + 3) * EMBED + c] = fmaxf(acc3, 0.0f);
}

// ---------------- R handling: bitmap-gated two-pass CSR + register SpMM ----------------

// fused init: head=-1, bitmap=0, cntR=0
__global__ void k_zero(int* __restrict__ head, unsigned* __restrict__ bitmap, int* __restrict__ cntR) {
    int i = blockIdx.x * blockDim.x + threadIdx.x;
    if (i < NUM_USERS) head[i] = -1;
    if (i < (NUM_USERS + 31) / 32) bitmap[i] = 0;
    if (i < BATCH) cntR[i] = 0;
}

__global__ void k_chain(const int* __restrict__ bu, int* __restrict__ head,
                        int* __restrict__ nxt, unsigned* __restrict__ bitmap, int n) {
    int i = blockIdx.x * blockDim.x + threadIdx.x;
    if (i < n) {
        int u = bu[i];
        nxt[i] = atomicExch(&head[u], i);
        atomicOr(&bitmap[u >> 5], 1u << (u & 31));
    }
}

// pass 1: bitmap test (12.5KB, L1-resident); head gather + histogram only for matched (~8%)
__global__ __launch_bounds__(256) void k_rcount(const int* __restrict__ rows,
                                                const unsigned* __restrict__ bitmap,
                                                const int* __restrict__ head,
                                                int* __restrict__ cntR, int nnz) {
    int e = blockIdx.x * blockDim.x + threadIdx.x;
    if (e >= nnz) return;
    int r = rows[e];
    if ((bitmap[(unsigned)r >> 5] >> (r & 31)) & 1u)
        atomicAdd(&cntR[head[r]], 1);
}

// exclusive scan over 8192 counts (one block), writes rowptr2[8193] and cursor copy
__global__ __launch_bounds__(1024) void k_rscan(const int* __restrict__ cnt,
                                                int* __restrict__ rowptr2,
                                                int* __restrict__ cur) {
    __shared__ int buf[1024];
    int t = threadIdx.x;
    int loc[8];
    int sum = 0;
#pragma unroll
    for (int q = 0; q < 8; ++q) { loc[q] = cnt[t * 8 + q]; sum += loc[q]; }
    buf[t] = sum;
    __syncthreads();
    for (int off = 1; off < 1024; off <<= 1) {
        int y = (t >= off) ? buf[t - off] : 0;
        __syncthreads();
        buf[t] += y;
        __syncthreads();
    }
    int excl = buf[t] - sum;
#pragma unroll
    for (int q = 0; q < 8; ++q) {
        rowptr2[t * 8 + q] = excl;
        cur[t * 8 + q]     = excl;
        excl += loc[q];
    }
    if (t == 1023) rowptr2[BATCH] = excl;
}

// pass 2: bitmap test; scatter matched (col,val) into per-slot CSR runs
__global__ __launch_bounds__(256) void k_rscatter(const int* __restrict__ rows,
                                                  const int* __restrict__ cols,
                                                  const float* __restrict__ vals,
                                                  const unsigned* __restrict__ bitmap,
                                                  const int* __restrict__ head,
                                                  int* __restrict__ cur,
                                                  int2* __restrict__ colval2, int nnz) {
    int e = blockIdx.x * blockDim.x + threadIdx.x;
    if (e >= nnz) return;
    int r = rows[e];
    if (!((bitmap[(unsigned)r >> 5] >> (r & 31)) & 1u)) return;
    int pos = atomicAdd(&cur[head[r]], 1);
    colval2[pos] = make_int2(cols[e], __float_as_int(vals[e]));
}

// per-chain-head gather SpMM, register accumulate, write once per slot along chain
__global__ __launch_bounds__(256) void k_rspmm(const int* __restrict__ rowptr2,
                                               const int2* __restrict__ colval2,
                                               const __hip_bfloat16* __restrict__ V16,
                                               const int* __restrict__ bu,
                                               const int* __restrict__ head,
                                               const int* __restrict__ nxt,
                                               float* __restrict__ out0) {
    int s    = blockIdx.x * (blockDim.x >> 6) + (threadIdx.x >> 6);
    int lane = threadIdx.x & 63;
    if (s >= BATCH) return;
    if (head[bu[s]] != s) return;       // only chain heads own edges
    int beg = rowptr2[s], end = rowptr2[s + 1];
    float acc = 0.0f;
    int j    = beg;
    int jend = beg + ((end - beg) & ~7);
    for (; j < jend; j += 8) {
        int2 cv[8];
#pragma unroll
        for (int u = 0; u < 8; ++u) cv[u] = colval2[j + u];
        float x[8];
#pragma unroll
        for (int u = 0; u < 8; ++u) x[u] = __bfloat162float(V16[(size_t)cv[u].x * EMBED + lane]);
#pragma unroll
        for (int u = 0; u < 8; ++u) acc = fmaf(__int_as_float(cv[u].y), x[u], acc);
    }
    for (; j < end; ++j)
        acc = fmaf(__int_as_float(colval2[j].y), __bfloat162float(V16[(size_t)colval2[j].x * EMBED + lane]), acc);
    int slot = s;
    while (slot >= 0) {
        out0[(size_t)slot * EMBED + lane] += acc;
        slot = nxt[slot];
    }
}

// ---------------- final gathers (bp/bn only, exact fp32 V) ----------------
__global__ void k_gather2(const float* __restrict__ V,
                          const int* __restrict__ bp, const int* __restrict__ bn,
                          float* __restrict__ out) {
    int i = blockIdx.x * blockDim.x + threadIdx.x;
    if (i >= BATCH * EMBED) return;
    int row = i >> 6, l = i & 63;
    out[BATCH * EMBED + i]     = V[(size_t)bp[row] * EMBED + l];
    out[2 * BATCH * EMBED + i] = V[(size_t)bn[row] * EMBED + l];
}

// ---------------- launch ----------------

extern "C" void kernel_launch(void* const* d_in, const int* in_sizes, int n_in,
                              void* d_out, int out_size, void* d_ws, size_t ws_size,
                              hipStream_t stream) {
    const int*   batch_user = (const int*)d_in[0];
    const int*   batch_pos  = (const int*)d_in[1];
    const int*   batch_neg  = (const int*)d_in[2];
    const float* U     = (const float*)d_in[3];
    const float* V     = (const float*)d_in[4];
    const float* W0    = (const float*)d_in[5];
    const float* b0    = (const float*)d_in[6];
    const float* W1    = (const float*)d_in[7];
    const float* b1    = (const float*)d_in[8];
    const int*   S_row = (const int*)d_in[9];
    const int*   S_col = (const int*)d_in[10];
    const float* S_val = (const float*)d_in[11];
    const int*   R_row = (const int*)d_in[12];
    const int*   R_col = (const int*)d_in[13];
    const float* R_val = (const float*)d_in[14];
    float* out = (float*)d_out;

    const size_t tabElems = (size_t)NUM_USERS * EMBED;   // 6.4M

    // workspace layout. Aliases: tmpE/colval2 <- A (dead windows).
    // X16 region (12.8 MB) sequentially holds U16 -> A16 -> V16.
    char* wsb = (char*)d_ws;
    size_t o = 0;
    float* A       = (float*)(wsb + o); o += tabElems * 4;            // U1 fp32 (alias: tmpE, colval2)
    float* B       = (float*)(wsb + o); o += tabElems * 4;            // agg fp32
    float* Agg2    = (float*)(wsb + o); o += (size_t)BATCH * EMBED * 4;
    int*   rowptrS = (int*)(wsb + o);   o += (NUM_USERS + 1) * 4;
    int*   cnt_t   = (int*)(wsb + o);   o += (size_t)NB * NCH * 4;
    int*   bsums   = (int*)(wsb + o);   o += 1024 * 4;
    int*   head    = (int*)(wsb + o);   o += NUM_USERS * 4;
    int*   nxt     = (int*)(wsb + o);   o += BATCH * 4;
    int*   cntR    = (int*)(wsb + o);   o += BATCH * 4;
    int*   rowptr2 = (int*)(wsb + o);   o += (BATCH + 1) * 4;
    int*   curR    = (int*)(wsb + o);   o += BATCH * 4;
    unsigned* bitmap = (unsigned*)(wsb + o); o += ((NUM_USERS + 31) / 32) * 4;
    o = (o + 7) & ~(size_t)7;
    int2*  colvalS = (int2*)(wsb + o);  o += (size_t)S_NNZ * 8;
    __hip_bfloat16* X16 = (__hip_bfloat16*)(wsb + o); o += tabElems * 2;

    int2* tmpE    = (int2*)A;
    int2* colval2 = (int2*)A;   // alias: A dead after k_layer_batch

    const int spmm_blocks  = (NUM_USERS * 64 + 255) / 256;
    const int layer_blocks = (NUM_USERS + 15) / 16;

    // ---- CSR of S: two-pass bucket sort ----
    k_p1hist<<<NCH, 256, 0, stream>>>(S_row, cnt_t);
    k_scan1<<<(NB * NCH) / 1024, 1024, 0, stream>>>(cnt_t, cnt_t, bsums, NB * NCH);
    k_scan2<<<1, 1024, 0, stream>>>(bsums, (NB * NCH) / 1024, &bsums[512]);
    k_scan3b<<<(NB * NCH) / 256, 256, 0, stream>>>(cnt_t, bsums, NB * NCH);
    k_p1scatter<<<NCH, 256, 0, stream>>>(S_row, S_col, S_val, cnt_t, tmpE);
    k_p2<<<NB, 512, 0, stream>>>(tmpE, cnt_t, rowptrS, colvalS);

    // ---- layer 0 (full): U16 table, SpMM1, layer v2 (emits A + A16) ----
    k_cvt<<<(int)((tabElems + 255) / 256), 256, 0, stream>>>(U, X16, (int)tabElems);
    k_spmm16<<<spmm_blocks, 256, 0, stream>>>(rowptrS, colvalS, X16, B, NUM_USERS);
    k_layer<<<layer_blocks, 256, 0, stream>>>(B, U, A, X16, W0, b0);   // X16 now = A16

    // ---- chain map + batch bitmap for R (user -> batch slots) ----
    k_zero<<<(NUM_USERS + 255) / 256, 256, 0, stream>>>(head, bitmap, cntR);
    k_chain<<<(BATCH + 255) / 256, 256, 0, stream>>>(batch_user, head, nxt, bitmap, BATCH);

    // ---- layer 1 (batch-restricted), writes u2 into out0 ----
    k_spmm_batch16<<<(BATCH * 64 + 255) / 256, 256, 0, stream>>>(rowptrS, colvalS, X16, batch_user, Agg2, BATCH);
    k_layer_batch<<<(BATCH + 15) / 16, 256, 0, stream>>>(Agg2, A, batch_user, out, W1, b1);  // A dead

    // ---- out0 += (R @ V)[batch rows]: bitmap-gated two-pass CSR + SpMM ----
    k_rcount<<<(R_NNZ + 255) / 256, 256, 0, stream>>>(R_row, bitmap, head, cntR, R_NNZ);
    k_rscan<<<1, 1024, 0, stream>>>(cntR, rowptr2, curR);
    k_rscatter<<<(R_NNZ + 255) / 256, 256, 0, stream>>>(R_row, R_col, R_val, bitmap, head, curR, colval2, R_NNZ);
    k_cvt<<<(int)(((size_t)NUM_ITEMS * EMBED + 255) / 256), 256, 0, stream>>>(V, X16, NUM_ITEMS * EMBED); // X16 now = V16
    k_rspmm<<<(BATCH * 64 + 255) / 256, 256, 0, stream>>>(rowptr2, colval2, X16, batch_user, head, nxt, out);

    // ---- bp/bn gathers (exact fp32 V) ----
    k_gather2<<<(BATCH * EMBED + 255) / 256, 256, 0, stream>>>(V, batch_pos, batch_neg, out);
}

// Round 8
// 511.640 us; speedup vs baseline: 1.4949x; 1.1285x over previous
//
#include <hip/hip_runtime.h>
#include <hip/hip_bf16.h>

#define NUM_USERS 100000
#define NUM_ITEMS 50000
#define EMBED     64
#define S_NNZ     (NUM_USERS * 32)
#define R_NNZ     (NUM_USERS * 50)
#define BATCH     8192

// bucket sort parameters: 256 buckets x 391 rows, 256 chunks x 12500 edges
#define NB    256
#define NCH   256
#define CHUNK (S_NNZ / NCH)      // 12500
#define BROWS 391                // 391*256 = 100096 >= NUM_USERS

#define SEGCAP 160               // per-slot R segment capacity (P(deg>160) ~ 1e-30)

// ---------------- two-pass bucket CSR build ----------------

// pass 1a: per-chunk bucket histogram; also fused init of head/bitmap/cntR
__global__ __launch_bounds__(256) void k_p1hist(const int* __restrict__ rows, int* __restrict__ cnt_t,
                                                int* __restrict__ head, unsigned* __restrict__ bitmap,
                                                int* __restrict__ cntR) {
    __shared__ int h[NB];
    int t = threadIdx.x, b = blockIdx.x;
    int gid = b * 256 + t;
    for (int i = gid; i < NUM_USERS; i += NB * 256) head[i] = -1;
    for (int i = gid; i < (NUM_USERS + 31) / 32; i += NB * 256) bitmap[i] = 0;
    for (int i = gid; i < BATCH; i += NB * 256) cntR[i] = 0;
    h[t] = 0;
    __syncthreads();
    int base = b * CHUNK;
    for (int i = t; i < CHUNK; i += 256) atomicAdd(&h[rows[base + i] / BROWS], 1);
    __syncthreads();
    cnt_t[t * NCH + b] = h[t];
}

__global__ __launch_bounds__(1024) void k_scan1(const int* __restrict__ cnt, int* __restrict__ excl,
                                                int* __restrict__ bsums, int n) {
    __shared__ int buf[1024];
    int t = threadIdx.x;
    int i = blockIdx.x * 1024 + t;
    int x = (i < n) ? cnt[i] : 0;
    buf[t] = x;
    __syncthreads();
    for (int off = 1; off < 1024; off <<= 1) {
        int y = (t >= off) ? buf[t - off] : 0;
        __syncthreads();
        buf[t] += y;
        __syncthreads();
    }
    if (i < n) excl[i] = buf[t] - x;
    if (t == 1023) bsums[blockIdx.x] = buf[1023];
}

__global__ __launch_bounds__(1024) void k_scan2(int* __restrict__ bsums, int nb, int* __restrict__ total_slot) {
    __shared__ int buf[1024];
    int t = threadIdx.x;
    int x = (t < nb) ? bsums[t] : 0;
    buf[t] = x;
    __syncthreads();
    for (int off = 1; off < 1024; off <<= 1) {
        int y = (t >= off) ? buf[t - off] : 0;
        __syncthreads();
        buf[t] += y;
        __syncthreads();
    }
    if (t < nb) bsums[t] = buf[t] - x;
    if (t == 1023) total_slot[0] = buf[1023];
}

__global__ void k_scan3b(int* __restrict__ a, const int* __restrict__ bsums, int n) {
    int i = blockIdx.x * blockDim.x + threadIdx.x;
    if (i < n) a[i] += bsums[i >> 10];
}

__global__ __launch_bounds__(256) void k_p1scatter(const int* __restrict__ rows, const int* __restrict__ cols,
                                                   const float* __restrict__ vals, const int* __restrict__ cnt_t,
                                                   int2* __restrict__ tmpE) {
    __shared__ int cur[NB];
    int t = threadIdx.x, b = blockIdx.x;
    cur[t] = cnt_t[t * NCH + b];
    __syncthreads();
    int base = b * CHUNK;
    for (int i = t; i < CHUNK; i += 256) {
        int e  = base + i;
        int r  = rows[e];
        int bk = r / BROWS;
        int pos = atomicAdd(&cur[bk], 1);
        tmpE[pos] = make_int2(((r - bk * BROWS) << 17) | cols[e], __float_as_int(vals[e]));
    }
}

__global__ __launch_bounds__(512) void k_p2(const int2* __restrict__ tmpE, const int* __restrict__ cnt_t,
                                            int* __restrict__ rowptr, int2* __restrict__ colval) {
    __shared__ int h[512];
    __shared__ int s[512];
    __shared__ int cur[512];
    int t = threadIdx.x, k = blockIdx.x;
    int beg = cnt_t[k * NCH];
    int end = (k < NB - 1) ? cnt_t[(k + 1) * NCH] : S_NNZ;
    h[t] = 0;
    __syncthreads();
    for (int j = beg + t; j < end; j += 512) atomicAdd(&h[((unsigned)tmpE[j].x) >> 17], 1);
    __syncthreads();
    s[t] = h[t];
    __syncthreads();
    for (int off = 1; off < 512; off <<= 1) {
        int y = (t >= off) ? s[t - off] : 0;
        __syncthreads();
        s[t] += y;
        __syncthreads();
    }
    int excl = s[t] - h[t];
    int gr   = k * BROWS + t;
    if (t <= BROWS && gr <= NUM_USERS) rowptr[gr] = beg + excl;
    cur[t] = beg + excl;
    __syncthreads();
    for (int j = beg + t; j < end; j += 512) {
        int2 e  = tmpE[j];
        int pos = atomicAdd(&cur[((unsigned)e.x) >> 17], 1);
        colval[pos] = make_int2(e.x & 0x1FFFF, e.y);
    }
}

// ---------------- converts ----------------
__global__ void k_cvt(const float* __restrict__ src, __hip_bfloat16* __restrict__ dst, int n) {
    int i = blockIdx.x * blockDim.x + threadIdx.x;
    if (i < n) dst[i] = __float2bfloat16(src[i]);
}

// ---------------- SpMM (CSR gather, bf16 table, unroll x8) — round-4 proven version ----
__global__ __launch_bounds__(256) void k_spmm16(const int* __restrict__ rowptr,
                                                const int2* __restrict__ colval,
                                                const __hip_bfloat16* __restrict__ X,
                                                float* __restrict__ Y, int n_rows) {
    int w    = blockIdx.x * (blockDim.x >> 6) + (threadIdx.x >> 6);
    int lane = threadIdx.x & 63;
    if (w >= n_rows) return;
    int beg = rowptr[w], end = rowptr[w + 1];
    float acc = 0.0f;
    int j    = beg;
    int jend = beg + ((end - beg) & ~7);
    for (; j < jend; j += 8) {
        int2 cv[8];
#pragma unroll
        for (int u = 0; u < 8; ++u) cv[u] = colval[j + u];
        float x[8];
#pragma unroll
        for (int u = 0; u < 8; ++u) x[u] = __bfloat162float(X[(size_t)cv[u].x * EMBED + lane]);
#pragma unroll
        for (int u = 0; u < 8; ++u) acc = fmaf(__int_as_float(cv[u].y), x[u], acc);
    }
    for (; j < end; ++j)
        acc = fmaf(__int_as_float(colval[j].y), __bfloat162float(X[(size_t)colval[j].x * EMBED + lane]), acc);
    Y[(size_t)w * EMBED + lane] = acc;
}

__global__ __launch_bounds__(256) void k_spmm_batch16(const int* __restrict__ rowptr,
                                                      const int2* __restrict__ colval,
                                                      const __hip_bfloat16* __restrict__ X,
                                                      const int* __restrict__ bu,
                                                      float* __restrict__ Agg2, int n) {
    int w    = blockIdx.x * (blockDim.x >> 6) + (threadIdx.x >> 6);
    int lane = threadIdx.x & 63;
    if (w >= n) return;
    int r   = bu[w];
    int beg = rowptr[r], end = rowptr[r + 1];
    float acc = 0.0f;
    int j    = beg;
    int jend = beg + ((end - beg) & ~7);
    for (; j < jend; j += 8) {
        int2 cv[8];
#pragma unroll
        for (int u = 0; u < 8; ++u) cv[u] = colval[j + u];
        float x[8];
#pragma unroll
        for (int u = 0; u < 8; ++u) x[u] = __bfloat162float(X[(size_t)cv[u].x * EMBED + lane]);
#pragma unroll
        for (int u = 0; u < 8; ++u) acc = fmaf(__int_as_float(cv[u].y), x[u], acc);
    }
    for (; j < end; ++j)
        acc = fmaf(__int_as_float(colval[j].y), __bfloat162float(X[(size_t)colval[j].x * EMBED + lane]), acc);
    Agg2[(size_t)w * EMBED + lane] = acc;
}

// ---------------- dense layers (v2) ----------------
// W transposed+XOR-swizzled in LDS; one conflict-free ds_read_b128 per 4 k-values,
// shared across 4 rows held in registers; X rows read as wave-uniform float4
// broadcasts from global (L1-resident).

__global__ __launch_bounds__(256) void k_layer(const float* __restrict__ Agg,
                                               const float* __restrict__ Uin,
                                               float* __restrict__ Uout,
                                               __hip_bfloat16* __restrict__ Uout16,
                                               const float* __restrict__ W,
                                               const float* __restrict__ b) {
    __shared__ __align__(16) float Wt[64 * 128];
    int t = threadIdx.x;
    for (int i = t; i < 128 * 64; i += 256) {
        int k = i >> 6, c = i & 63;
        Wt[c * 128 + ((((k >> 2) ^ (c & 7)) << 2) | (k & 3))] = W[i];
    }
    int rl = __builtin_amdgcn_readfirstlane(t >> 6);   // wave id 0..3 (wave-uniform)
    int c  = t & 63;
    int rbase = blockIdx.x * 16 + rl * 4;              // 6250*16 = 100000 exact, no guard
    __syncthreads();
    const float4* Wt4 = (const float4*)Wt;
    int  csw   = c & 7;
    int  cbase = c * 32;
    const float4* a0 = (const float4*)(Agg + (size_t)(rbase + 0) * EMBED);
    const float4* a1 = (const float4*)(Agg + (size_t)(rbase + 1) * EMBED);
    const float4* a2 = (const float4*)(Agg + (size_t)(rbase + 2) * EMBED);
    const float4* a3 = (const float4*)(Agg + (size_t)(rbase + 3) * EMBED);
    const float4* u0 = (const float4*)(Uin + (size_t)(rbase + 0) * EMBED);
    const float4* u1 = (const float4*)(Uin + (size_t)(rbase + 1) * EMBED);
    const float4* u2 = (const float4*)(Uin + (size_t)(rbase + 2) * EMBED);
    const float4* u3 = (const float4*)(Uin + (size_t)(rbase + 3) * EMBED);
    float bias = b[c];
    float acc0 = bias, acc1 = bias, acc2 = bias, acc3 = bias;
#pragma unroll 4
    for (int k4 = 0; k4 < 16; ++k4) {
        float4 w4 = Wt4[cbase + (k4 ^ csw)];
        float4 x0 = a0[k4], x1 = a1[k4], x2 = a2[k4], x3 = a3[k4];
        acc0 = fmaf(x0.x, w4.x, acc0); acc0 = fmaf(x0.y, w4.y, acc0); acc0 = fmaf(x0.z, w4.z, acc0); acc0 = fmaf(x0.w, w4.w, acc0);
        acc1 = fmaf(x1.x, w4.x, acc1); acc1 = fmaf(x1.y, w4.y, acc1); acc1 = fmaf(x1.z, w4.z, acc1); acc1 = fmaf(x1.w, w4.w, acc1);
        acc2 = fmaf(x2.x, w4.x, acc2); acc2 = fmaf(x2.y, w4.y, acc2); acc2 = fmaf(x2.z, w4.z, acc2); acc2 = fmaf(x2.w, w4.w, acc2);
        acc3 = fmaf(x3.x, w4.x, acc3); acc3 = fmaf(x3.y, w4.y, acc3); acc3 = fmaf(x3.z, w4.z, acc3); acc3 = fmaf(x3.w, w4.w, acc3);
    }
#pragma unroll 4
    for (int k4 = 16; k4 < 32; ++k4) {
        float4 w4 = Wt4[cbase + (k4 ^ csw)];
        float4 x0 = u0[k4 - 16], x1 = u1[k4 - 16], x2 = u2[k4 - 16], x3 = u3[k4 - 16];
        acc0 = fmaf(x0.x, w4.x, acc0); acc0 = fmaf(x0.y, w4.y, acc0); acc0 = fmaf(x0.z, w4.z, acc0); acc0 = fmaf(x0.w, w4.w, acc0);
        acc1 = fmaf(x1.x, w4.x, acc1); acc1 = fmaf(x1.y, w4.y, acc1); acc1 = fmaf(x1.z, w4.z, acc1); acc1 = fmaf(x1.w, w4.w, acc1);
        acc2 = fmaf(x2.x, w4.x, acc2); acc2 = fmaf(x2.y, w4.y, acc2); acc2 = fmaf(x2.z, w4.z, acc2); acc2 = fmaf(x2.w, w4.w, acc2);
        acc3 = fmaf(x3.x, w4.x, acc3); acc3 = fmaf(x3.y, w4.y, acc3); acc3 = fmaf(x3.z, w4.z, acc3); acc3 = fmaf(x3.w, w4.w, acc3);
    }
    float v0 = fmaxf(acc0, 0.0f), v1 = fmaxf(acc1, 0.0f), v2 = fmaxf(acc2, 0.0f), v3 = fmaxf(acc3, 0.0f);
    Uout[(size_t)(rbase + 0) * EMBED + c] = v0;
    Uout[(size_t)(rbase + 1) * EMBED + c] = v1;
    Uout[(size_t)(rbase + 2) * EMBED + c] = v2;
    Uout[(size_t)(rbase + 3) * EMBED + c] = v3;
    Uout16[(size_t)(rbase + 0) * EMBED + c] = __float2bfloat16(v0);
    Uout16[(size_t)(rbase + 1) * EMBED + c] = __float2bfloat16(v1);
    Uout16[(size_t)(rbase + 2) * EMBED + c] = __float2bfloat16(v2);
    Uout16[(size_t)(rbase + 3) * EMBED + c] = __float2bfloat16(v3);
}

// + fused bp/bn gather epilogue (replaces k_gather2)
__global__ __launch_bounds__(256) void k_layer_batch(const float* __restrict__ Agg2,
                                                     const float* __restrict__ Uin,
                                                     const int* __restrict__ bu,
                                                     float* __restrict__ out0,
                                                     const float* __restrict__ W,
                                                     const float* __restrict__ b,
                                                     const float* __restrict__ V,
                                                     const int* __restrict__ bp,
                                                     const int* __restrict__ bn) {
    __shared__ __align__(16) float Wt[64 * 128];
    int t = threadIdx.x;
    for (int i = t; i < 128 * 64; i += 256) {
        int k = i >> 6, c = i & 63;
        Wt[c * 128 + ((((k >> 2) ^ (c & 7)) << 2) | (k & 3))] = W[i];
    }
    int rl = __builtin_amdgcn_readfirstlane(t >> 6);
    int c  = t & 63;
    int sbase = blockIdx.x * 16 + rl * 4;              // 512*16 = 8192 exact
    int r0 = bu[sbase + 0], r1 = bu[sbase + 1], r2 = bu[sbase + 2], r3 = bu[sbase + 3];
    __syncthreads();
    const float4* Wt4 = (const float4*)Wt;
    int  csw   = c & 7;
    int  cbase = c * 32;
    const float4* a0 = (const float4*)(Agg2 + (size_t)(sbase + 0) * EMBED);
    const float4* a1 = (const float4*)(Agg2 + (size_t)(sbase + 1) * EMBED);
    const float4* a2 = (const float4*)(Agg2 + (size_t)(sbase + 2) * EMBED);
    const float4* a3 = (const float4*)(Agg2 + (size_t)(sbase + 3) * EMBED);
    const float4* u0 = (const float4*)(Uin + (size_t)r0 * EMBED);
    const float4* u1 = (const float4*)(Uin + (size_t)r1 * EMBED);
    const float4* u2 = (const float4*)(Uin + (size_t)r2 * EMBED);
    const float4* u3 = (const float4*)(Uin + (size_t)r3 * EMBED);
    float bias = b[c];
    float acc0 = bias, acc1 = bias, acc2 = bias, acc3 = bias;
#pragma unroll 4
    for (int k4 = 0; k4 < 16; ++k4) {
        float4 w4 = Wt4[cbase + (k4 ^ csw)];
        float4 x0 = a0[k4], x1 = a1[k4], x2 = a2[k4], x3 = a3[k4];
        acc0 = fmaf(x0.x, w4.x, acc0); acc0 = fmaf(x0.y, w4.y, acc0); acc0 = fmaf(x0.z, w4.z, acc0); acc0 = fmaf(x0.w, w4.w, acc0);
        acc1 = fmaf(x1.x, w4.x, acc1); acc1 = fmaf(x1.y, w4.y, acc1); acc1 = fmaf(x1.z, w4.z, acc1); acc1 = fmaf(x1.w, w4.w, acc1);
        acc2 = fmaf(x2.x, w4.x, acc2); acc2 = fmaf(x2.y, w4.y, acc2); acc2 = fmaf(x2.z, w4.z, acc2); acc2 = fmaf(x2.w, w4.w, acc2);
        acc3 = fmaf(x3.x, w4.x, acc3); acc3 = fmaf(x3.y, w4.y, acc3); acc3 = fmaf(x3.z, w4.z, acc3); acc3 = fmaf(x3.w, w4.w, acc3);
    }
#pragma unroll 4
    for (int k4 = 16; k4 < 32; ++k4) {
        float4 w4 = Wt4[cbase + (k4 ^ csw)];
        float4 x0 = u0[k4 - 16], x1 = u1[k4 - 16], x2 = u2[k4 - 16], x3 = u3[k4 - 16];
        acc0 = fmaf(x0.x, w4.x, acc0); acc0 = fmaf(x0.y, w4.y, acc0); acc0 = fmaf(x0.z, w4.z, acc0); acc0 = fmaf(x0.w, w4.w, acc0);
        acc1 = fmaf(x1.x, w4.x, acc1); acc1 = fmaf(x1.y, w4.y, acc1); acc1 = fmaf(x1.z, w4.z, acc1); acc1 = fmaf(x1.w, w4.w, acc1);
        acc2 = fmaf(x2.x, w4.x, acc2); acc2 = fmaf(x2.y, w4.y, acc2); acc2 = fmaf(x2.z, w4.z, acc2); acc2 = fmaf(x2.w, w4.w, acc2);
        acc3 = fmaf(x3.x, w4.x, acc3); acc3 = fmaf(x3.y, w4.y, acc3); acc3 = fmaf(x3.z, w4.z, acc3); acc3 = fmaf(x3.w, w4.w, acc3);
    }
    out0[(size_t)(sbase + 0) * EMBED + c] = fmaxf(acc0, 0.0f);
    out0[(size_t)(sbase + 1) * EMBED + c] = fmaxf(acc1, 0.0f);
    out0[(size_t)(sbase + 2) * EMBED + c] = fmaxf(acc2, 0.0f);
    out0[(size_t)(sbase + 3) * EMBED + c] = fmaxf(acc3, 0.0f);
    // fused bp/bn gathers (exact fp32 V)
#pragma unroll
    for (int q = 0; q < 4; ++q) {
        int s = sbase + q;
        out0[(size_t)(BATCH + s) * EMBED + c]     = V[(size_t)bp[s] * EMBED + c];
        out0[(size_t)(2 * BATCH + s) * EMBED + c] = V[(size_t)bn[s] * EMBED + c];
    }
}

// ---------------- R handling: bitmap filter -> fixed segments -> register SpMM ----------------

__global__ void k_chain(const int* __restrict__ bu, int* __restrict__ head,
                        int* __restrict__ nxt, unsigned* __restrict__ bitmap, int n) {
    int i = blockIdx.x * blockDim.x + threadIdx.x;
    if (i < n) {
        int u = bu[i];
        nxt[i] = atomicExch(&head[u], i);
        atomicOr(&bitmap[u >> 5], 1u << (u & 31));
    }
}

// single 5M-edge pass: bitmap-gated segment fill; also fused V->bf16 convert
__global__ __launch_bounds__(256) void k_rseg(const int* __restrict__ rows,
                                              const int* __restrict__ cols,
                                              const float* __restrict__ vals,
                                              const unsigned* __restrict__ bitmap,
                                              const int* __restrict__ head,
                                              int* __restrict__ cntR,
                                              int2* __restrict__ seg, int nnz,
                                              const float* __restrict__ V,
                                              __hip_bfloat16* __restrict__ V16) {
    int e = blockIdx.x * blockDim.x + threadIdx.x;
    if (e < NUM_ITEMS * EMBED) V16[e] = __float2bfloat16(V[e]);
    if (e >= nnz) return;
    int r = rows[e];
    if (!((bitmap[(unsigned)r >> 5] >> (r & 31)) & 1u)) return;
    int s   = head[r];
    int pos = atomicAdd(&cntR[s], 1);
    if (pos < SEGCAP) seg[s * SEGCAP + pos] = make_int2(cols[e], __float_as_int(vals[e]));
}

// per-chain-head gather SpMM over its segment; write once per slot along chain
__global__ __launch_bounds__(256) void k_rspmm(const int* __restrict__ cntR,
                                               const int2* __restrict__ seg,
                                               const __hip_bfloat16* __restrict__ V16,
                                               const int* __restrict__ bu,
                                               const int* __restrict__ head,
                                               const int* __restrict__ nxt,
                                               float* __restrict__ out0) {
    int s    = blockIdx.x * (blockDim.x >> 6) + (threadIdx.x >> 6);
    int lane = threadIdx.x & 63;
    if (s >= BATCH) return;
    if (head[bu[s]] != s) return;       // only chain heads own edges
    int n = cntR[s];
    if (n > SEGCAP) n = SEGCAP;
    const int2* cv2 = seg + (size_t)s * SEGCAP;
    float acc = 0.0f;
    int j    = 0;
    int jend = n & ~7;
    for (; j < jend; j += 8) {
        int2 cv[8];
#pragma unroll
        for (int u = 0; u < 8; ++u) cv[u] = cv2[j + u];
        float x[8];
#pragma unroll
        for (int u = 0; u < 8; ++u) x[u] = __bfloat162float(V16[(size_t)cv[u].x * EMBED + lane]);
#pragma unroll
        for (int u = 0; u < 8; ++u) acc = fmaf(__int_as_float(cv[u].y), x[u], acc);
    }
    for (; j < n; ++j)
        acc = fmaf(__int_as_float(cv2[j].y), __bfloat162float(V16[(size_t)cv2[j].x * EMBED + lane]), acc);
    int slot = s;
    while (slot >= 0) {
        out0[(size_t)slot * EMBED + lane] += acc;
        slot = nxt[slot];
    }
}

// ---------------- launch ----------------

extern "C" void kernel_launch(void* const* d_in, const int* in_sizes, int n_in,
                              void* d_out, int out_size, void* d_ws, size_t ws_size,
                              hipStream_t stream) {
    const int*   batch_user = (const int*)d_in[0];
    const int*   batch_pos  = (const int*)d_in[1];
    const int*   batch_neg  = (const int*)d_in[2];
    const float* U     = (const float*)d_in[3];
    const float* V     = (const float*)d_in[4];
    const float* W0    = (const float*)d_in[5];
    const float* b0    = (const float*)d_in[6];
    const float* W1    = (const float*)d_in[7];
    const float* b1    = (const float*)d_in[8];
    const int*   S_row = (const int*)d_in[9];
    const int*   S_col = (const int*)d_in[10];
    const float* S_val = (const float*)d_in[11];
    const int*   R_row = (const int*)d_in[12];
    const int*   R_col = (const int*)d_in[13];
    const float* R_val = (const float*)d_in[14];
    float* out = (float*)d_out;

    const size_t tabElems = (size_t)NUM_USERS * EMBED;   // 6.4M

    // workspace layout. Aliases: tmpE <- A (dead window); seg <- B (dead after k_layer).
    // X16 region (12.8 MB) sequentially holds U16 -> A16 -> V16.
    char* wsb = (char*)d_ws;
    size_t o = 0;
    float* A       = (float*)(wsb + o); o += tabElems * 4;            // U1 fp32 (alias: tmpE)
    float* B       = (float*)(wsb + o); o += tabElems * 4;            // agg fp32 (alias: seg)
    float* Agg2    = (float*)(wsb + o); o += (size_t)BATCH * EMBED * 4;
    int*   rowptrS = (int*)(wsb + o);   o += (NUM_USERS + 1) * 4;
    int*   cnt_t   = (int*)(wsb + o);   o += (size_t)NB * NCH * 4;
    int*   bsums   = (int*)(wsb + o);   o += 1024 * 4;
    int*   head    = (int*)(wsb + o);   o += NUM_USERS * 4;
    int*   nxt     = (int*)(wsb + o);   o += BATCH * 4;
    int*   cntR    = (int*)(wsb + o);   o += BATCH * 4;
    unsigned* bitmap = (unsigned*)(wsb + o); o += ((NUM_USERS + 31) / 32) * 4;
    o = (o + 7) & ~(size_t)7;
    int2*  colvalS = (int2*)(wsb + o);  o += (size_t)S_NNZ * 8;
    __hip_bfloat16* X16 = (__hip_bfloat16*)(wsb + o); o += tabElems * 2;

    int2* tmpE = (int2*)A;
    int2* seg  = (int2*)B;   // alias: B dead after k_layer; 8192*160*8B = 10.5MB < 25.6MB

    const int spmm_blocks  = (NUM_USERS * 64 + 255) / 256;
    const int layer_blocks = (NUM_USERS + 15) / 16;

    // ---- CSR of S: two-pass bucket sort (p1hist also inits head/bitmap/cntR) ----
    k_p1hist<<<NCH, 256, 0, stream>>>(S_row, cnt_t, head, bitmap, cntR);
    k_scan1<<<(NB * NCH) / 1024, 1024, 0, stream>>>(cnt_t, cnt_t, bsums, NB * NCH);
    k_scan2<<<1, 1024, 0, stream>>>(bsums, (NB * NCH) / 1024, &bsums[512]);
    k_scan3b<<<(NB * NCH) / 256, 256, 0, stream>>>(cnt_t, bsums, NB * NCH);
    k_p1scatter<<<NCH, 256, 0, stream>>>(S_row, S_col, S_val, cnt_t, tmpE);
    k_p2<<<NB, 512, 0, stream>>>(tmpE, cnt_t, rowptrS, colvalS);

    // ---- layer 0 (full): U16 table, SpMM1, layer v2 (emits A + A16) ----
    k_cvt<<<(int)((tabElems + 255) / 256), 256, 0, stream>>>(U, X16, (int)tabElems);
    k_spmm16<<<spmm_blocks, 256, 0, stream>>>(rowptrS, colvalS, X16, B, NUM_USERS);
    k_layer<<<layer_blocks, 256, 0, stream>>>(B, U, A, X16, W0, b0);   // X16 now = A16; B dead

    // ---- chain map + batch bitmap for R (user -> batch slots) ----
    k_chain<<<(BATCH + 255) / 256, 256, 0, stream>>>(batch_user, head, nxt, bitmap, BATCH);

    // ---- layer 1 (batch-restricted), writes u2 into out0; fused bp/bn gathers ----
    k_spmm_batch16<<<(BATCH * 64 + 255) / 256, 256, 0, stream>>>(rowptrS, colvalS, X16, batch_user, Agg2, BATCH);
    k_layer_batch<<<(BATCH + 15) / 16, 256, 0, stream>>>(Agg2, A, batch_user, out, W1, b1,
                                                         V, batch_pos, batch_neg);  // A dead

    // ---- out0 += (R @ V)[batch rows]: bitmap filter -> segments -> SpMM (cvtV fused) ----
    k_rseg<<<(R_NNZ + 255) / 256, 256, 0, stream>>>(R_row, R_col, R_val, bitmap, head, cntR, seg, R_NNZ,
                                                    V, X16);  // X16 now = V16
    k_rspmm<<<(BATCH * 64 + 255) / 256, 256, 0, stream>>>(cntR, seg, X16, batch_user, head, nxt, out);
}